// Round 5
// baseline (249.669 us; speedup 1.0000x reference)
//
#include <hip/hip_runtime.h>

#define BGRAPH  16
#define NPG     8192     // 2^13 nodes per graph
#define DIM     256
#define KKEEP   4096     // 2^12 kept per graph
#define TOTALN  (BGRAPH * NPG)     // 131072
#define TOTKEEP (BGRAPH * KKEEP)   // 65536
#define NEDGE   2097152
#define NBUCK   4096     // 12-bit buckets

using u16 = unsigned short;
using u32 = unsigned int;
using u64 = unsigned long long;

// descending-sortable transform of f32 bits: smaller kd <=> larger float
__device__ __forceinline__ u32 desc_key(float f) {
  u32 b = __float_as_uint(f);
  u32 s = b ^ ((b & 0x80000000u) ? 0xFFFFFFFFu : 0x80000000u);  // asc-sortable
  return ~s;                                                     // desc-sortable
}

// ---------------- kernel 1: score = tanh((x . w) / ||w||) -------------------
__global__ __launch_bounds__(256) void k_score(const float* __restrict__ x,
                                               const float* __restrict__ w,
                                               float* __restrict__ score) {
  int gid  = blockIdx.x * 256 + threadIdx.x;
  int row  = gid >> 6;
  int lane = gid & 63;
  const float4 x4 = *reinterpret_cast<const float4*>(x + (size_t)row * DIM + lane * 4);
  const float4 w4 = *reinterpret_cast<const float4*>(w + lane * 4);
  double dot = (double)x4.x * w4.x + (double)x4.y * w4.y
             + (double)x4.z * w4.z + (double)x4.w * w4.w;
  double w2  = (double)w4.x * w4.x + (double)w4.y * w4.y
             + (double)w4.z * w4.z + (double)w4.w * w4.w;
  #pragma unroll
  for (int off = 32; off > 0; off >>= 1) {
    dot += __shfl_xor(dot, off, 64);
    w2  += __shfl_xor(w2,  off, 64);
  }
  if (lane == 0) score[row] = tanhf((float)(dot / sqrt(w2)));
}

// ---------------- kernel 2: O(N) bucketed stable rank -----------------------
// One block (1024 thr) per graph. Counting-sort by top-12 bits of the
// desc-sortable key, then exact stable rank within bucket. Comparator is
// identical to the O(N^2) version: (key, original index) ascending.
__global__ __launch_bounds__(1024) void k_rank(const float* __restrict__ score,
                                               u16* __restrict__ map16) {
  __shared__ u32 hist[NBUCK];      // 16 KB
  __shared__ u32 skey[NPG];        // 32 KB
  __shared__ u16 sidx[NPG];        // 16 KB   (total = 64 KB exactly)
  u32* wsum = (u32*)sidx;          // overlay: used only during scan phase

  const int g    = blockIdx.x;
  const int tid  = threadIdx.x;
  const int wid  = tid >> 6;
  const int lane = tid & 63;
  const float* gs = score + (size_t)g * NPG;

  // zero histogram
  #pragma unroll
  for (int i = 0; i < NBUCK / 1024; ++i) hist[tid + i * 1024] = 0;
  __syncthreads();

  // pass 1: histogram (score reads are L2-hot, 32 KB/graph)
  #pragma unroll
  for (int i = 0; i < NPG / 1024; ++i) {
    u32 kd = desc_key(gs[tid + i * 1024]);
    atomicAdd(&hist[kd >> 20], 1u);
  }
  __syncthreads();

  // exclusive prefix sum over 4096 buckets (4 per thread + 2-level wave scan)
  u32 h0 = hist[4 * tid], h1 = hist[4 * tid + 1],
      h2 = hist[4 * tid + 2], h3 = hist[4 * tid + 3];
  u32 s  = h0 + h1 + h2 + h3;
  u32 inc = s;
  #pragma unroll
  for (int off = 1; off < 64; off <<= 1) {
    u32 t = __shfl_up(inc, off, 64);
    if (lane >= off) inc += t;
  }
  if (lane == 63) wsum[wid] = inc;
  __syncthreads();
  if (tid < 16) {
    u32 v = wsum[tid], vi = v;
    #pragma unroll
    for (int off = 1; off < 16; off <<= 1) {
      u32 t = __shfl_up(vi, off, 64);
      if (tid >= off) vi += t;
    }
    wsum[tid] = vi - v;              // exclusive wave offset
  }
  __syncthreads();
  u32 excl = inc - s + wsum[wid];
  __syncthreads();                   // wsum reads done before sidx overlay reuse
  hist[4 * tid]     = excl;
  hist[4 * tid + 1] = excl + h0;
  hist[4 * tid + 2] = excl + h0 + h1;
  hist[4 * tid + 3] = excl + h0 + h1 + h2;
  __syncthreads();

  // pass 2: scatter into bucket order; hist[b] becomes bucket END
  #pragma unroll
  for (int i = 0; i < NPG / 1024; ++i) {
    int idx = tid + i * 1024;
    u32 kd  = desc_key(gs[idx]);
    u32 pos = atomicAdd(&hist[kd >> 20], 1u);
    skey[pos] = kd;
    sidx[pos] = (u16)idx;
  }
  __syncthreads();

  // rank: lower-bucket count (= start) + stable within-bucket count
  for (int p = tid; p < NPG; p += 1024) {
    u32 key = skey[p];
    u16 idx = sidx[p];
    u32 b     = key >> 20;
    u32 start = b ? hist[b - 1] : 0;   // end of b-1 == start of b (empty-safe)
    u32 end   = hist[b];
    u32 cnt   = 0;
    for (u32 q = start; q < end; ++q) {
      u32 kq = skey[q];
      cnt += (kq < key) || (kq == key && sidx[q] < idx);
    }
    u32 rank = start + cnt;
    map16[(size_t)g * NPG + idx] = (rank < KKEEP) ? (u16)rank : (u16)0xFFFFu;
  }
}

// ---------------- kernel 3: inverted gather (f32 out) -----------------------
__global__ __launch_bounds__(256) void k_gather(const float* __restrict__ x,
                                                const float* __restrict__ score,
                                                const u16* __restrict__ map16,
                                                float* __restrict__ x_out) {
  int gid  = blockIdx.x * 256 + threadIdx.x;
  int node = gid >> 6;
  int lane = gid & 63;
  u16 rk = map16[node];
  if (rk == 0xFFFFu) return;
  int nid = ((node >> 13) << 12) | (int)rk;      // graph*K + rank
  float val = score[node];
  const float4 v = *reinterpret_cast<const float4*>(x + (size_t)node * DIM + lane * 4);
  float4 o;
  o.x = v.x * val; o.y = v.y * val; o.z = v.z * val; o.w = v.w * val;
  *reinterpret_cast<float4*>(x_out + (size_t)nid * DIM + lane * 4) = o;
}

// ---------------- kernel 4: edge filter + reindex (f32 out) -----------------
__global__ __launch_bounds__(256) void k_edges(const int* __restrict__ ei,
                                               const u16* __restrict__ map16,
                                               float* __restrict__ e_out) {
  int e = blockIdx.x * 256 + threadIdx.x;
  int a = ei[e];
  int b = ei[NEDGE + e];
  u16 ra = map16[a];
  u16 rb = map16[b];
  bool kept = (ra != 0xFFFFu) && (rb != 0xFFFFu);
  e_out[e]         = kept ? (float)(((a >> 13) << 12) | (int)ra) : -1.0f;
  e_out[NEDGE + e] = kept ? (float)(((b >> 13) << 12) | (int)rb) : -1.0f;
}

// ---------------- kernel 5: batch_out (runs last, clobbers map16 staging) ---
__global__ __launch_bounds__(256) void k_batch(float* __restrict__ b_out) {
  int i = blockIdx.x * 256 + threadIdx.x;
  b_out[i] = (float)(i >> 12);                   // nid / K = graph id
}

extern "C" void kernel_launch(void* const* d_in, const int* in_sizes, int n_in,
                              void* d_out, int out_size, void* d_ws, size_t ws_size,
                              hipStream_t stream) {
  const float* x  = nullptr;
  const int*   ei = nullptr;
  const float* w  = nullptr;
  for (int i = 0; i < n_in; ++i) {
    if      (in_sizes[i] == TOTALN * DIM) x  = (const float*)d_in[i];
    else if (in_sizes[i] == 2 * NEDGE)    ei = (const int*)d_in[i];
    else if (in_sizes[i] == DIM)          w  = (const float*)d_in[i];
  }
  (void)d_ws; (void)ws_size; (void)out_size;

  // d_out: FLOAT32, layout [x_out 16777216 | e_out 4194304 | b_out 65536]
  float* out   = (float*)d_out;
  float* x_out = out;
  float* e_out = out + (size_t)TOTKEEP * DIM;    // f32 idx 16777216
  float* b_out = e_out + 2 * (size_t)NEDGE;      // f32 idx 20971520

  // zero-workspace staging inside d_out (consumed before clobbered):
  float* score = e_out;                          // 512 KB at e_out head
  u16*   map16 = (u16*)b_out;                    // 256 KB = exactly b_out region

  hipLaunchKernelGGL(k_score,  dim3(TOTALN / 4),    dim3(256),  0, stream, x, w, score);
  hipLaunchKernelGGL(k_rank,   dim3(BGRAPH),        dim3(1024), 0, stream, score, map16);
  hipLaunchKernelGGL(k_gather, dim3(TOTALN / 4),    dim3(256),  0, stream, x, score, map16, x_out);
  hipLaunchKernelGGL(k_edges,  dim3(NEDGE / 256),   dim3(256),  0, stream, ei, map16, e_out);
  hipLaunchKernelGGL(k_batch,  dim3(TOTKEEP / 256), dim3(256),  0, stream, b_out);
}

// Round 6
// 103.494 us; speedup vs baseline: 2.4124x; 2.4124x over previous
//
#include <hip/hip_runtime.h>

#define BGRAPH  16
#define NPG     8192     // 2^13 nodes per graph
#define DIM     256
#define KKEEP   4096     // 2^12 kept per graph
#define TOTALN  (BGRAPH * NPG)     // 131072
#define TOTKEEP (BGRAPH * KKEEP)   // 65536
#define NEDGE   2097152
#define NBUCK   8192     // 13-bit buckets

using u16 = unsigned short;
using u32 = unsigned int;

// descending-sortable transform of f32 bits: smaller kd <=> larger float
__device__ __forceinline__ u32 desc_key(float f) {
  u32 b = __float_as_uint(f);
  u32 s = b ^ ((b & 0x80000000u) ? 0xFFFFFFFFu : 0x80000000u);  // asc-sortable
  return ~s;                                                     // desc-sortable
}

// ---------------- kernel 1: score = tanh((x . w) / ||w||) -------------------
__global__ __launch_bounds__(256) void k_score(const float* __restrict__ x,
                                               const float* __restrict__ w,
                                               float* __restrict__ score) {
  int gid  = blockIdx.x * 256 + threadIdx.x;
  int row  = gid >> 6;
  int lane = gid & 63;
  const float4 x4 = *reinterpret_cast<const float4*>(x + (size_t)row * DIM + lane * 4);
  const float4 w4 = *reinterpret_cast<const float4*>(w + lane * 4);
  double dot = (double)x4.x * w4.x + (double)x4.y * w4.y
             + (double)x4.z * w4.z + (double)x4.w * w4.w;
  double w2  = (double)w4.x * w4.x + (double)w4.y * w4.y
             + (double)w4.z * w4.z + (double)w4.w * w4.w;
  #pragma unroll
  for (int off = 32; off > 0; off >>= 1) {
    dot += __shfl_xor(dot, off, 64);
    w2  += __shfl_xor(w2,  off, 64);
  }
  if (lane == 0) score[row] = tanhf((float)(dot / sqrt(w2)));
}

// ---------------- kernel 2: O(N) bucketed stable rank (branchless) ----------
// One block (1024 thr) per graph. Counting-sort by top-13 bits of the
// desc-sortable key; within-bucket element = (low-19 key bits << 13) | idx,
// so a SINGLE u32 compare is the exact stable (score desc, idx asc) order.
__global__ __launch_bounds__(1024) void k_rank(const float* __restrict__ score,
                                               u16* __restrict__ map16) {
  __shared__ u32 hist[NBUCK];      // 32 KB
  __shared__ u32 skey[NPG];        // 32 KB  (total 64 KB)
  u32* wsum = skey;                // overlay: dead until scatter phase

  const int g    = blockIdx.x;
  const int tid  = threadIdx.x;
  const int wid  = tid >> 6;
  const int lane = tid & 63;
  const float* gs = score + (size_t)g * NPG;

  // zero histogram
  #pragma unroll
  for (int i = 0; i < NBUCK / 1024; ++i) hist[tid + i * 1024] = 0;
  __syncthreads();

  // pass 1: histogram
  #pragma unroll
  for (int i = 0; i < NPG / 1024; ++i)
    atomicAdd(&hist[desc_key(gs[tid + i * 1024]) >> 19], 1u);
  __syncthreads();

  // exclusive prefix sum over 8192 buckets: 8/thread + 2-level wave scan
  u32 h[8], s = 0;
  #pragma unroll
  for (int j = 0; j < 8; ++j) { h[j] = hist[8 * tid + j]; s += h[j]; }
  u32 inc = s;
  #pragma unroll
  for (int off = 1; off < 64; off <<= 1) {
    u32 t = __shfl_up(inc, off, 64);
    if (lane >= off) inc += t;
  }
  if (lane == 63) wsum[wid] = inc;
  __syncthreads();
  if (tid < 16) {
    u32 v = wsum[tid], vi = v;
    #pragma unroll
    for (int off = 1; off < 16; off <<= 1) {
      u32 t = __shfl_up(vi, off, 64);
      if (tid >= off) vi += t;
    }
    wsum[tid] = vi - v;              // exclusive wave offset
  }
  __syncthreads();
  u32 run = inc - s + wsum[wid];     // exclusive start of this thread's 8 buckets
  #pragma unroll
  for (int j = 0; j < 8; ++j) { u32 hv = h[j]; hist[8 * tid + j] = run; run += hv; }
  __syncthreads();                   // wsum reads done; skey safe to write

  // pass 2: scatter; hist[b] becomes bucket END
  #pragma unroll
  for (int i = 0; i < NPG / 1024; ++i) {
    int idx = tid + i * 1024;
    u32 kd  = desc_key(gs[idx]);
    u32 pos = atomicAdd(&hist[kd >> 19], 1u);
    skey[pos] = (kd << 13) | (u32)idx;           // low19 key bits + 13-bit idx
  }
  __syncthreads();

  // rank = bucket start + branchless within-bucket count
  #pragma unroll
  for (int i = 0; i < NPG / 1024; ++i) {
    int p   = tid + i * 1024;
    u32 key = skey[p];
    int idx = (int)(key & 0x1FFFu);
    u32 b   = desc_key(gs[idx]) >> 19;           // bucket id (L1-hot re-read)
    u32 start = b ? hist[b - 1] : 0;             // end of b-1 == start of b
    u32 end   = hist[b];
    u32 cnt = 0, q = start;
    for (; q + 4 <= end; q += 4) {               // branchless, pipelined
      u32 a0 = skey[q], a1 = skey[q + 1], a2 = skey[q + 2], a3 = skey[q + 3];
      cnt += (a0 < key) + (a1 < key) + (a2 < key) + (a3 < key);
    }
    for (; q < end; ++q) cnt += (skey[q] < key);
    u32 rank = start + cnt;
    map16[(size_t)g * NPG + idx] = (rank < KKEEP) ? (u16)rank : (u16)0xFFFFu;
  }
}

// ---------------- kernel 3: inverted gather (f32 out) -----------------------
__global__ __launch_bounds__(256) void k_gather(const float* __restrict__ x,
                                                const float* __restrict__ score,
                                                const u16* __restrict__ map16,
                                                float* __restrict__ x_out) {
  int gid  = blockIdx.x * 256 + threadIdx.x;
  int node = gid >> 6;
  int lane = gid & 63;
  u16 rk = map16[node];
  if (rk == 0xFFFFu) return;
  int nid = ((node >> 13) << 12) | (int)rk;      // graph*K + rank
  float val = score[node];
  const float4 v = *reinterpret_cast<const float4*>(x + (size_t)node * DIM + lane * 4);
  float4 o;
  o.x = v.x * val; o.y = v.y * val; o.z = v.z * val; o.w = v.w * val;
  *reinterpret_cast<float4*>(x_out + (size_t)nid * DIM + lane * 4) = o;
}

// ---------------- kernel 4: edge filter + reindex (f32 out) -----------------
__global__ __launch_bounds__(256) void k_edges(const int* __restrict__ ei,
                                               const u16* __restrict__ map16,
                                               float* __restrict__ e_out) {
  int e = blockIdx.x * 256 + threadIdx.x;
  int a = ei[e];
  int b = ei[NEDGE + e];
  u16 ra = map16[a];
  u16 rb = map16[b];
  bool kept = (ra != 0xFFFFu) && (rb != 0xFFFFu);
  e_out[e]         = kept ? (float)(((a >> 13) << 12) | (int)ra) : -1.0f;
  e_out[NEDGE + e] = kept ? (float)(((b >> 13) << 12) | (int)rb) : -1.0f;
}

// ---------------- kernel 5: batch_out (runs last, clobbers map16 staging) ---
__global__ __launch_bounds__(256) void k_batch(float* __restrict__ b_out) {
  int i = blockIdx.x * 256 + threadIdx.x;
  b_out[i] = (float)(i >> 12);                   // nid / K = graph id
}

extern "C" void kernel_launch(void* const* d_in, const int* in_sizes, int n_in,
                              void* d_out, int out_size, void* d_ws, size_t ws_size,
                              hipStream_t stream) {
  const float* x  = nullptr;
  const int*   ei = nullptr;
  const float* w  = nullptr;
  for (int i = 0; i < n_in; ++i) {
    if      (in_sizes[i] == TOTALN * DIM) x  = (const float*)d_in[i];
    else if (in_sizes[i] == 2 * NEDGE)    ei = (const int*)d_in[i];
    else if (in_sizes[i] == DIM)          w  = (const float*)d_in[i];
  }
  (void)d_ws; (void)ws_size; (void)out_size;

  // d_out: FLOAT32, layout [x_out 16777216 | e_out 4194304 | b_out 65536]
  float* out   = (float*)d_out;
  float* x_out = out;
  float* e_out = out + (size_t)TOTKEEP * DIM;    // f32 idx 16777216
  float* b_out = e_out + 2 * (size_t)NEDGE;      // f32 idx 20971520

  // zero-workspace staging inside d_out (consumed before clobbered):
  float* score = e_out;                          // 512 KB at e_out head
  u16*   map16 = (u16*)b_out;                    // 256 KB = exactly b_out region

  hipLaunchKernelGGL(k_score,  dim3(TOTALN / 4),    dim3(256),  0, stream, x, w, score);
  hipLaunchKernelGGL(k_rank,   dim3(BGRAPH),        dim3(1024), 0, stream, score, map16);
  hipLaunchKernelGGL(k_gather, dim3(TOTALN / 4),    dim3(256),  0, stream, x, score, map16, x_out);
  hipLaunchKernelGGL(k_edges,  dim3(NEDGE / 256),   dim3(256),  0, stream, ei, map16, e_out);
  hipLaunchKernelGGL(k_batch,  dim3(TOTKEEP / 256), dim3(256),  0, stream, b_out);
}

// Round 7
// 94.197 us; speedup vs baseline: 2.6505x; 1.0987x over previous
//
#include <hip/hip_runtime.h>

#define BGRAPH  16
#define NPG     8192     // 2^13 nodes per graph
#define DIM     256
#define KKEEP   4096     // 2^12 kept per graph
#define TOTALN  (BGRAPH * NPG)     // 131072
#define TOTKEEP (BGRAPH * KKEEP)   // 65536
#define NEDGE   2097152
#define NBUCK   8192     // 13-bit buckets

using u16 = unsigned short;
using u32 = unsigned int;

// descending-sortable transform of f32 bits: smaller kd <=> larger float
__device__ __forceinline__ u32 desc_key(float f) {
  u32 b = __float_as_uint(f);
  u32 s = b ^ ((b & 0x80000000u) ? 0xFFFFFFFFu : 0x80000000u);  // asc-sortable
  return ~s;                                                     // desc-sortable
}

// ---------------- kernel 1: score = tanh((x . w) / ||w||) -------------------
__global__ __launch_bounds__(256) void k_score(const float* __restrict__ x,
                                               const float* __restrict__ w,
                                               float* __restrict__ score) {
  int gid  = blockIdx.x * 256 + threadIdx.x;
  int row  = gid >> 6;
  int lane = gid & 63;
  const float4 x4 = *reinterpret_cast<const float4*>(x + (size_t)row * DIM + lane * 4);
  const float4 w4 = *reinterpret_cast<const float4*>(w + lane * 4);
  double dot = (double)x4.x * w4.x + (double)x4.y * w4.y
             + (double)x4.z * w4.z + (double)x4.w * w4.w;
  double w2  = (double)w4.x * w4.x + (double)w4.y * w4.y
             + (double)w4.z * w4.z + (double)w4.w * w4.w;
  #pragma unroll
  for (int off = 32; off > 0; off >>= 1) {
    dot += __shfl_xor(dot, off, 64);
    w2  += __shfl_xor(w2,  off, 64);
  }
  if (lane == 0) score[row] = tanhf((float)(dot / sqrt(w2)));
}

// ---------------- kernel 2a: bucket-sort (1 block/graph, serial part only) --
// Counting-sort by top-13 bits of desc-sortable key. Emits to GLOBAL staging:
//   skey[g][pos]  = (kd<<13)|idx   (within-bucket stable comparator in one u32)
//   sbkt[g][pos]  = bucket id
//   bends[g][b]   = bucket end offset
__global__ __launch_bounds__(1024) void k_sort(const float* __restrict__ score,
                                               u32* __restrict__ skey,
                                               u16* __restrict__ sbkt,
                                               u32* __restrict__ bends) {
  __shared__ u32 hist[NBUCK];      // 32 KB
  __shared__ u32 wsum[16];
  const int g    = blockIdx.x;
  const int tid  = threadIdx.x;
  const int wid  = tid >> 6;
  const int lane = tid & 63;
  const float* gs = score + (size_t)g * NPG;
  u32* skg = skey  + (size_t)g * NPG;
  u16* sbg = sbkt  + (size_t)g * NPG;
  u32* beg = bends + (size_t)g * NBUCK;

  #pragma unroll
  for (int i = 0; i < NBUCK / 1024; ++i) hist[tid + i * 1024] = 0;
  __syncthreads();

  u32 kd_[NPG / 1024];                       // keys cached in registers
  #pragma unroll
  for (int i = 0; i < NPG / 1024; ++i) {
    kd_[i] = desc_key(gs[tid + i * 1024]);
    atomicAdd(&hist[kd_[i] >> 19], 1u);
  }
  __syncthreads();

  // exclusive prefix sum over 8192 buckets: 8/thread + 2-level wave scan
  u32 h[8], s = 0;
  #pragma unroll
  for (int j = 0; j < 8; ++j) { h[j] = hist[8 * tid + j]; s += h[j]; }
  u32 inc = s;
  #pragma unroll
  for (int off = 1; off < 64; off <<= 1) {
    u32 t = __shfl_up(inc, off, 64);
    if (lane >= off) inc += t;
  }
  if (lane == 63) wsum[wid] = inc;
  __syncthreads();
  if (tid < 16) {
    u32 v = wsum[tid], vi = v;
    #pragma unroll
    for (int off = 1; off < 16; off <<= 1) {
      u32 t = __shfl_up(vi, off, 64);
      if (tid >= off) vi += t;
    }
    wsum[tid] = vi - v;                      // exclusive wave offset
  }
  __syncthreads();
  u32 run = inc - s + wsum[wid];
  #pragma unroll
  for (int j = 0; j < 8; ++j) { u32 hv = h[j]; hist[8 * tid + j] = run; run += hv; }
  __syncthreads();

  // scatter; hist[b] becomes bucket END
  #pragma unroll
  for (int i = 0; i < NPG / 1024; ++i) {
    int idx = tid + i * 1024;
    u32 kd  = kd_[i];
    u32 b   = kd >> 19;
    u32 pos = atomicAdd(&hist[b], 1u);
    skg[pos] = (kd << 13) | (u32)idx;
    sbg[pos] = (u16)b;
  }
  __syncthreads();
  #pragma unroll
  for (int i = 0; i < NBUCK / 1024; ++i) {
    int b = tid + i * 1024;
    beg[b] = hist[b];
  }
}

// ---------------- kernel 2b: rank count (full-occupancy, 1 thr/element) -----
__global__ __launch_bounds__(512) void k_count(const u32* __restrict__ skey,
                                               const u16* __restrict__ sbkt,
                                               const u32* __restrict__ bends,
                                               u16* __restrict__ map16) {
  const int g = blockIdx.x >> 4;
  const int p = (blockIdx.x & 15) * 512 + (int)threadIdx.x;
  const u32* skg = skey  + (size_t)g * NPG;
  const u32* beg = bends + (size_t)g * NBUCK;
  u32 key = skg[p];
  u32 b   = sbkt[(size_t)g * NPG + p];
  u32 start = b ? beg[b - 1] : 0;
  int idx = (int)(key & 0x1FFFu);
  u16* mp = map16 + ((size_t)g << 13);
  if (start >= KKEEP) { mp[idx] = (u16)0xFFFFu; return; }   // early drop
  u32 end = beg[b];
  u32 cnt = 0, q = start;
  for (; q + 4 <= end; q += 4) {             // branchless, L1-broadcast reads
    cnt += (skg[q]     < key) + (skg[q + 1] < key)
         + (skg[q + 2] < key) + (skg[q + 3] < key);
  }
  for (; q < end; ++q) cnt += (skg[q] < key);
  u32 rank = start + cnt;
  mp[idx] = (rank < KKEEP) ? (u16)rank : (u16)0xFFFFu;
}

// ---------------- kernel 3: inverted gather (f32 out) -----------------------
__global__ __launch_bounds__(256) void k_gather(const float* __restrict__ x,
                                                const float* __restrict__ score,
                                                const u16* __restrict__ map16,
                                                float* __restrict__ x_out) {
  int gid  = blockIdx.x * 256 + threadIdx.x;
  int node = gid >> 6;
  int lane = gid & 63;
  u16 rk = map16[node];
  if (rk == 0xFFFFu) return;
  int nid = ((node >> 13) << 12) | (int)rk;  // graph*K + rank
  float val = score[node];
  const float4 v = *reinterpret_cast<const float4*>(x + (size_t)node * DIM + lane * 4);
  float4 o;
  o.x = v.x * val; o.y = v.y * val; o.z = v.z * val; o.w = v.w * val;
  *reinterpret_cast<float4*>(x_out + (size_t)nid * DIM + lane * 4) = o;
}

// ---------------- kernel 4: edge filter + reindex (f32 out) -----------------
__global__ __launch_bounds__(256) void k_edges(const int* __restrict__ ei,
                                               const u16* __restrict__ map16,
                                               float* __restrict__ e_out) {
  int e = blockIdx.x * 256 + threadIdx.x;
  int a = ei[e];
  int b = ei[NEDGE + e];
  u16 ra = map16[a];
  u16 rb = map16[b];
  bool kept = (ra != 0xFFFFu) && (rb != 0xFFFFu);
  e_out[e]         = kept ? (float)(((a >> 13) << 12) | (int)ra) : -1.0f;
  e_out[NEDGE + e] = kept ? (float)(((b >> 13) << 12) | (int)rb) : -1.0f;
}

// ---------------- kernel 5: batch_out (runs last, clobbers map16 staging) ---
__global__ __launch_bounds__(256) void k_batch(float* __restrict__ b_out) {
  int i = blockIdx.x * 256 + threadIdx.x;
  b_out[i] = (float)(i >> 12);               // nid / K = graph id
}

extern "C" void kernel_launch(void* const* d_in, const int* in_sizes, int n_in,
                              void* d_out, int out_size, void* d_ws, size_t ws_size,
                              hipStream_t stream) {
  const float* x  = nullptr;
  const int*   ei = nullptr;
  const float* w  = nullptr;
  for (int i = 0; i < n_in; ++i) {
    if      (in_sizes[i] == TOTALN * DIM) x  = (const float*)d_in[i];
    else if (in_sizes[i] == 2 * NEDGE)    ei = (const int*)d_in[i];
    else if (in_sizes[i] == DIM)          w  = (const float*)d_in[i];
  }
  (void)d_ws; (void)ws_size; (void)out_size;

  // d_out: FLOAT32, layout [x_out 16777216 | e_out 4194304 | b_out 65536]
  float* out   = (float*)d_out;
  float* x_out = out;
  float* e_out = out + (size_t)TOTKEEP * DIM;    // f32 idx 16777216
  float* b_out = e_out + 2 * (size_t)NEDGE;      // f32 idx 20971520

  // zero-workspace staging inside d_out (all consumed before clobbered):
  float* score = e_out;                          // 512 KB  (dead after k_gather; k_edges clobbers)
  u16*   map16 = (u16*)b_out;                    // 256 KB  (dead after k_edges; k_batch clobbers)
  u32*   skey  = (u32*)x_out;                    // 512 KB  ┐
  u32*   bends = (u32*)(x_out + TOTALN);         // 512 KB  ├ x_out head (dead after k_count;
  u16*   sbkt  = (u16*)(x_out + 2 * TOTALN);     // 256 KB  ┘  k_gather clobbers)

  hipLaunchKernelGGL(k_score,  dim3(TOTALN / 4),    dim3(256),  0, stream, x, w, score);
  hipLaunchKernelGGL(k_sort,   dim3(BGRAPH),        dim3(1024), 0, stream, score, skey, sbkt, bends);
  hipLaunchKernelGGL(k_count,  dim3(BGRAPH * 16),   dim3(512),  0, stream, skey, sbkt, bends, map16);
  hipLaunchKernelGGL(k_gather, dim3(TOTALN / 4),    dim3(256),  0, stream, x, score, map16, x_out);
  hipLaunchKernelGGL(k_edges,  dim3(NEDGE / 256),   dim3(256),  0, stream, ei, map16, e_out);
  hipLaunchKernelGGL(k_batch,  dim3(TOTKEEP / 256), dim3(256),  0, stream, b_out);
}